// Round 3
// baseline (215.992 us; speedup 1.0000x reference)
//
#include <hip/hip_runtime.h>
#include <stdint.h>

#define LOG2E       1.4426950408889634f
#define INV_SQRT32  0.17677669529663687f

using bf16x8 = __attribute__((ext_vector_type(8))) short;
using f32x4  = __attribute__((ext_vector_type(4))) float;

__device__ __forceinline__ unsigned short f2bf(float f) {
  union { float f; uint32_t u; } v; v.f = f;
  uint32_t r = v.u + 0x7fffu + ((v.u >> 16) & 1u);   // RNE
  return (unsigned short)(r >> 16);
}

typedef const __attribute__((address_space(1))) void* gas_ptr;
typedef __attribute__((address_space(3))) void*       las_ptr;
__device__ __forceinline__ void load_lds16(const void* g, void* l) {
  // wave-uniform LDS base; HW scatters lane i -> base + i*16
  __builtin_amdgcn_global_load_lds((gas_ptr)g, (las_ptr)l, 16, 0, 0);
}

// ---------- kernel 1: W (fp32) -> Wcat bf16 [768][256]; bias -> bias_cat fp32 [768]
__global__ __launch_bounds__(256) void convert_w(
    const float* __restrict__ wq, const float* __restrict__ bq,
    const float* __restrict__ wk, const float* __restrict__ bk,
    const float* __restrict__ wv, const float* __restrict__ bv,
    unsigned short* __restrict__ Wcat, float* __restrict__ biasc) {
  int idx = (blockIdx.x * 256 + threadIdx.x) * 4;   // flat into 768*256
  int p = idx >> 16;                                // which projection
  int rem = idx & 0xffff;
  const float* src = (p == 0) ? wq : (p == 1) ? wk : wv;
  float4 v = *(const float4*)(src + rem);
  ushort4 o;
  o.x = f2bf(v.x); o.y = f2bf(v.y); o.z = f2bf(v.z); o.w = f2bf(v.w);
  *(ushort4*)(Wcat + idx) = o;
  if (blockIdx.x < 3) {
    const float* sb = (blockIdx.x == 0) ? bq : (blockIdx.x == 1) ? bk : bv;
    biasc[blockIdx.x * 256 + threadIdx.x] = sb[threadIdx.x];
  }
}

// ---------- kernel 2: x fp32 [b][c][s] -> Xt bf16 [b][s][c]
__global__ __launch_bounds__(256) void transpose_x(const float* __restrict__ x,
                                                   unsigned short* __restrict__ xt) {
  __shared__ float tile[64 * 65];
  int b = blockIdx.z;
  int s0 = blockIdx.x * 64, c0 = blockIdx.y * 64;
  int t = threadIdx.x;
  int sl = t & 63, g = t >> 6;
  const float* xp = x + ((size_t)(b * 256 + c0)) * 4096 + s0 + sl;
#pragma unroll
  for (int ii = 0; ii < 16; ++ii) {
    int cl = g * 16 + ii;
    tile[cl * 65 + sl] = xp[(size_t)cl * 4096];
  }
  __syncthreads();
  // store phase: each thread packs 8 contiguous c into one uint4 store
#pragma unroll
  for (int it = 0; it < 2; ++it) {
    int idx = it * 256 + t;
    int s_loc = idx >> 3, cb = (idx & 7) * 8;
    unsigned short ov[8];
#pragma unroll
    for (int j = 0; j < 8; ++j) ov[j] = f2bf(tile[(cb + j) * 65 + s_loc]);
    *(uint4*)&xt[((size_t)(b * 4096 + s0 + s_loc)) * 256 + c0 + cb] = *(uint4*)ov;
  }
}

// ---------- kernel 3: qkv[b][768][4096] bf16 = Wcat[768][256] * Xt[b][4096][256]^T + bias
// v4: depth-3 counted-vmcnt pipeline (vmcnt(8) steady state, ~2 iters latency cover),
//     swapped-operand MFMA (D rows = s) -> ushort4 vectorized epilogue stores.
__global__ __launch_bounds__(256) void gemm_qkv(
    const unsigned short* __restrict__ Wc, const float* __restrict__ biasc,
    const unsigned short* __restrict__ Xt, unsigned short* __restrict__ qkv) {
  __shared__ unsigned short As[3][128 * 32];
  __shared__ unsigned short Bs[3][128 * 32];
  int blk = blockIdx.x;
  int b = blk / 192;
  int rest = blk - b * 192;
  int mt = rest >> 5, nt = rest & 31;
  int m0 = mt * 128, n0 = nt * 128;
  int tid = threadIdx.x;
  int lane = tid & 63, wave = tid >> 6;
  int quad = lane >> 4, rt = lane & 15;
  int wm = wave >> 1, wn = wave & 1;

  f32x4 acc[4][4];
#pragma unroll
  for (int i = 0; i < 4; ++i)
#pragma unroll
    for (int j = 0; j < 4; ++j) acc[i][j] = (f32x4){0.f, 0.f, 0.f, 0.f};

  // staging: each wave stages rows [wave*32, wave*32+32) of both tiles.
  // LDS dest linear (lane i -> base + 16*i): row = lane>>2, slot = lane&3.
  // swizzle: physical slot p at row r holds logical slot p ^ ((r>>1)&3)
  int lr = lane >> 2;
  int sl_src = (lane & 3) ^ ((lane >> 3) & 3);
  const unsigned short* gA0 = Wc + (size_t)(m0 + wave * 32 + lr) * 256 + sl_src * 8;
  const unsigned short* gA1 = gA0 + 16 * 256;
  const unsigned short* gB0 = Xt + ((size_t)b * 4096 + n0 + wave * 32 + lr) * 256 + sl_src * 8;
  const unsigned short* gB1 = gB0 + 16 * 256;

#define STAGE(bufi, ko)                                        \
  do {                                                         \
    load_lds16(gA0 + (ko), &As[bufi][wave * 1024]);            \
    load_lds16(gA1 + (ko), &As[bufi][wave * 1024 + 512]);      \
    load_lds16(gB0 + (ko), &Bs[bufi][wave * 1024]);            \
    load_lds16(gB1 + (ko), &Bs[bufi][wave * 1024 + 512]);      \
  } while (0)

  int rsw = (quad ^ ((rt >> 1) & 3)) * 8;   // swizzled read slot (elements)

  // prologue: 3 chunks in flight
  STAGE(0, 0);
  STAGE(1, 32);
  STAGE(2, 64);

  // Ledger (4 loads/STAGE, in-order): top of iter k, outstanding = chunks k..min(k+2,7).
  //   k<=5: 12 loads -> vmcnt(8) retires chunk k; k=6: 8 -> vmcnt(4); k=7: 4 -> vmcnt(0).
  //   end of iter k (k+3<8): stage chunk k+3 into buf k%3 (just-consumed, barrier-protected).
#define KSTEP(kc, WAITN)                                                      \
  do {                                                                        \
    asm volatile("s_waitcnt vmcnt(" #WAITN ")" ::: "memory");                 \
    __builtin_amdgcn_s_barrier();                                             \
    __builtin_amdgcn_sched_barrier(0);                                        \
    const unsigned short* A_ = As[(kc) % 3];                                  \
    const unsigned short* B_ = Bs[(kc) % 3];                                  \
    bf16x8 af[4], bfr[4];                                                     \
    _Pragma("unroll")                                                         \
    for (int mi = 0; mi < 4; ++mi)                                            \
      af[mi] = *(const bf16x8*)&A_[(wm * 64 + mi * 16 + rt) * 32 + rsw];      \
    _Pragma("unroll")                                                         \
    for (int ni = 0; ni < 4; ++ni)                                            \
      bfr[ni] = *(const bf16x8*)&B_[(wn * 64 + ni * 16 + rt) * 32 + rsw];     \
    _Pragma("unroll")                                                         \
    for (int mi = 0; mi < 4; ++mi)                                            \
      _Pragma("unroll")                                                       \
      for (int ni = 0; ni < 4; ++ni)                                          \
        acc[mi][ni] = __builtin_amdgcn_mfma_f32_16x16x32_bf16(bfr[ni], af[mi], acc[mi][ni], 0, 0, 0); \
    __builtin_amdgcn_sched_barrier(0);                                        \
    __builtin_amdgcn_s_barrier();                                             \
    if ((kc) + 3 < 8) STAGE((kc) % 3, ((kc) + 3) * 32);                       \
  } while (0)

  KSTEP(0, 8);
  KSTEP(1, 8);
  KSTEP(2, 8);
  KSTEP(3, 8);
  KSTEP(4, 8);
  KSTEP(5, 8);
  KSTEP(6, 4);
  KSTEP(7, 0);
#undef KSTEP
#undef STAGE

  // epilogue: swapped MFMA -> D[row = s-local (quad*4+r)][col = o-local (rt)]
  // lane holds 4 consecutive s at fixed o -> one 8B store per (mi,ni)
  size_t obase = (size_t)b * 768;
#pragma unroll
  for (int mi = 0; mi < 4; ++mi) {
    int o = m0 + wm * 64 + mi * 16 + rt;
    float bo = biasc[o];
    size_t rowb = (obase + o) * 4096;
#pragma unroll
    for (int ni = 0; ni < 4; ++ni) {
      int s = n0 + wn * 64 + ni * 16 + quad * 4;
      ushort4 st;
      st.x = f2bf(acc[mi][ni][0] + bo);
      st.y = f2bf(acc[mi][ni][1] + bo);
      st.z = f2bf(acc[mi][ni][2] + bo);
      st.w = f2bf(acc[mi][ni][3] + bo);
      *(ushort4*)&qkv[rowb + s] = st;
    }
  }
}

// ---------- kernel 4: per-(b, o) 64x64 attention, v2 (wave-quadrant, 2 barriers)
// Q/K fragments direct from global (L2-hot). S in regs; softmax in-register via
// shfl_xor over rt-group + tiny LDS cross-wave exchange. PV computes O^T so the
// store is float4-vectorized. V gathered at top, LDS-written after softmax (T14).
// LDS: Vt[64][72]bf16 9216 | Ps[64][72]bf16 9216 | redm[128]f32 | reds[128]f32 = 19456 B
__global__ __launch_bounds__(256) void attn(const unsigned short* __restrict__ qkv,
                                            float* __restrict__ out) {
  __shared__ unsigned short Vt[64 * 72];
  __shared__ unsigned short Ps[64 * 72];
  __shared__ float redm[128];   // [wn][64 rows] partial rowmax
  __shared__ float reds[128];   // [wn][64 rows] partial rowsum

  int blk = blockIdx.x;
  int b = blk >> 8, o = blk & 255;
  int t = threadIdx.x;
  size_t base = ((size_t)b * 768 + o) * 4096;
  const unsigned short* qg = qkv + base;
  const unsigned short* kg = qkv + base + (size_t)256 * 4096;
  const unsigned short* vg = qkv + base + (size_t)512 * 4096;

  int lane = t & 63, wave = t >> 6;
  int rt = lane & 15, quad = lane >> 4;
  int wm = wave >> 1, wn = wave & 1;

  // --- issue V gather early: thread covers w = t&63, g = (t>>6)*16 .. +15 (coalesced 128B rows)
  int vw = t & 63, gb = (t >> 6) * 16;
  unsigned short vv[16];
#pragma unroll
  for (int j = 0; j < 16; ++j) vv[j] = vg[(size_t)(gb + j) * 64 + vw];

  // --- S = Q K^T : direct-global fragments, 2x2 tiles of 16x16 per wave, K=64
  // A-frag row h = wm*32 + tm*16 + rt ; B-frag row g = wn*32 + tn*16 + rt ; k = w
  f32x4 accs[2][2];
#pragma unroll
  for (int i = 0; i < 2; ++i)
#pragma unroll
    for (int j = 0; j < 2; ++j) accs[i][j] = (f32x4){0.f, 0.f, 0.f, 0.f};
#pragma unroll
  for (int ks = 0; ks < 2; ++ks) {
    int kk = ks * 32 + quad * 8;
    bf16x8 a0 = *(const bf16x8*)&qg[(wm * 32 + rt) * 64 + kk];
    bf16x8 a1 = *(const bf16x8*)&qg[(wm * 32 + 16 + rt) * 64 + kk];
    bf16x8 b0 = *(const bf16x8*)&kg[(wn * 32 + rt) * 64 + kk];
    bf16x8 b1 = *(const bf16x8*)&kg[(wn * 32 + 16 + rt) * 64 + kk];
    accs[0][0] = __builtin_amdgcn_mfma_f32_16x16x32_bf16(a0, b0, accs[0][0], 0, 0, 0);
    accs[0][1] = __builtin_amdgcn_mfma_f32_16x16x32_bf16(a0, b1, accs[0][1], 0, 0, 0);
    accs[1][0] = __builtin_amdgcn_mfma_f32_16x16x32_bf16(a1, b0, accs[1][0], 0, 0, 0);
    accs[1][1] = __builtin_amdgcn_mfma_f32_16x16x32_bf16(a1, b1, accs[1][1], 0, 0, 0);
  }

  // S in D-layout: lane holds S[h][g], h = wm*32+tm*16+quad*4+r, g = wn*32+tn*16+rt.
  float sv[2][2][4];
#pragma unroll
  for (int tm = 0; tm < 2; ++tm)
#pragma unroll
    for (int tn = 0; tn < 2; ++tn)
#pragma unroll
      for (int r = 0; r < 4; ++r) sv[tm][tn][r] = accs[tm][tn][r] * INV_SQRT32;

  // per-row max over this wave's 32 g-cols: per-lane (2 tn) then shfl_xor over rt bits
  float pmax[2][4];
#pragma unroll
  for (int tm = 0; tm < 2; ++tm)
#pragma unroll
    for (int r = 0; r < 4; ++r) {
      float m = fmaxf(sv[tm][0][r], sv[tm][1][r]);
      m = fmaxf(m, __shfl_xor(m, 1));
      m = fmaxf(m, __shfl_xor(m, 2));
      m = fmaxf(m, __shfl_xor(m, 4));
      m = fmaxf(m, __shfl_xor(m, 8));
      pmax[tm][r] = m;
    }
  if (rt == 0) {
#pragma unroll
    for (int tm = 0; tm < 2; ++tm)
#pragma unroll
      for (int r = 0; r < 4; ++r)
        redm[wn * 64 + wm * 32 + tm * 16 + quad * 4 + r] = pmax[tm][r];
  }
  __syncthreads();   // barrier 1: rowmax exchange

  float psum[2][4];
  unsigned short pb[2][2][4];
#pragma unroll
  for (int tm = 0; tm < 2; ++tm)
#pragma unroll
    for (int r = 0; r < 4; ++r) {
      int h = wm * 32 + tm * 16 + quad * 4 + r;
      float mr = fmaxf(redm[h], redm[64 + h]);
      float acc_s = 0.f;
#pragma unroll
      for (int tn = 0; tn < 2; ++tn) {
        float p = exp2f((sv[tm][tn][r] - mr) * LOG2E);
        acc_s += p;
        pb[tm][tn][r] = f2bf(p);
      }
      acc_s += __shfl_xor(acc_s, 1);
      acc_s += __shfl_xor(acc_s, 2);
      acc_s += __shfl_xor(acc_s, 4);
      acc_s += __shfl_xor(acc_s, 8);
      psum[tm][r] = acc_s;
    }
  if (rt == 0) {
#pragma unroll
    for (int tm = 0; tm < 2; ++tm)
#pragma unroll
      for (int r = 0; r < 4; ++r)
        reds[wn * 64 + wm * 32 + tm * 16 + quad * 4 + r] = psum[tm][r];
  }
  // P -> LDS (transposed access needed by PV A/B frags)
#pragma unroll
  for (int tm = 0; tm < 2; ++tm)
#pragma unroll
    for (int tn = 0; tn < 2; ++tn)
#pragma unroll
      for (int r = 0; r < 4; ++r)
        Ps[(wm * 32 + tm * 16 + quad * 4 + r) * 72 + wn * 32 + tn * 16 + rt] = pb[tm][tn][r];
  // V -> LDS transposed (global latency was covered by S+softmax)
  *(uint4*)&Vt[vw * 72 + gb]     = ((uint4*)vv)[0];
  *(uint4*)&Vt[vw * 72 + gb + 8] = ((uint4*)vv)[1];
  __syncthreads();   // barrier 2: Ps + reds + Vt visible

  // --- O^T = V^T P^T : A-frag = Vt[w][g], B-frag = Ps[h][g], contract g
  // D[row = w-local (quad*4+r)][col = h-local (rt)]
  f32x4 acco[2][2];
#pragma unroll
  for (int i = 0; i < 2; ++i)
#pragma unroll
    for (int j = 0; j < 2; ++j) acco[i][j] = (f32x4){0.f, 0.f, 0.f, 0.f};
#pragma unroll
  for (int ks = 0; ks < 2; ++ks) {
    int kk = ks * 32 + quad * 8;
    bf16x8 va0 = *(const bf16x8*)&Vt[(wm * 32 + rt) * 72 + kk];
    bf16x8 va1 = *(const bf16x8*)&Vt[(wm * 32 + 16 + rt) * 72 + kk];
    bf16x8 p0  = *(const bf16x8*)&Ps[(wn * 32 + rt) * 72 + kk];
    bf16x8 p1  = *(const bf16x8*)&Ps[(wn * 32 + 16 + rt) * 72 + kk];
    acco[0][0] = __builtin_amdgcn_mfma_f32_16x16x32_bf16(va0, p0, acco[0][0], 0, 0, 0);
    acco[0][1] = __builtin_amdgcn_mfma_f32_16x16x32_bf16(va0, p1, acco[0][1], 0, 0, 0);
    acco[1][0] = __builtin_amdgcn_mfma_f32_16x16x32_bf16(va1, p0, acco[1][0], 0, 0, 0);
    acco[1][1] = __builtin_amdgcn_mfma_f32_16x16x32_bf16(va1, p1, acco[1][1], 0, 0, 0);
  }

  float* op = out + ((size_t)(b * 256 + o)) * 4096;
#pragma unroll
  for (int hi = 0; hi < 2; ++hi) {
    int h = wn * 32 + hi * 16 + rt;
    float rinv = 1.f / (reds[h] + reds[64 + h]);
#pragma unroll
    for (int wi = 0; wi < 2; ++wi) {
      int w0 = wm * 32 + wi * 16 + quad * 4;
      float4 st;
      st.x = acco[wi][hi][0] * rinv;
      st.y = acco[wi][hi][1] * rinv;
      st.z = acco[wi][hi][2] * rinv;
      st.w = acco[wi][hi][3] * rinv;
      *(float4*)&op[h * 64 + w0] = st;
    }
  }
}

extern "C" void kernel_launch(void* const* d_in, const int* in_sizes, int n_in,
                              void* d_out, int out_size, void* d_ws, size_t ws_size,
                              hipStream_t stream) {
  const float* x  = (const float*)d_in[0];
  const float* wq = (const float*)d_in[1];
  const float* bq = (const float*)d_in[2];
  const float* wk = (const float*)d_in[3];
  const float* bk = (const float*)d_in[4];
  const float* wv = (const float*)d_in[5];
  const float* bv = (const float*)d_in[6];
  float* out = (float*)d_out;

  // workspace layout (bytes): Wcat bf16 393216 | bias fp32 3072 | Xt bf16 33554432 | qkv bf16 100663296
  char* ws = (char*)d_ws;
  unsigned short* Wcat  = (unsigned short*)ws;
  float*          biasc = (float*)(ws + 393216);
  unsigned short* Xt    = (unsigned short*)(ws + 396288);
  unsigned short* qkv   = (unsigned short*)(ws + 396288 + 33554432);

  hipLaunchKernelGGL(convert_w, dim3(192), dim3(256), 0, stream,
                     wq, bq, wk, bk, wv, bv, Wcat, biasc);
  hipLaunchKernelGGL(transpose_x, dim3(64, 4, 16), dim3(256), 0, stream, x, Xt);
  hipLaunchKernelGGL(gemm_qkv, dim3(3072), dim3(256), 0, stream, Wcat, biasc, Xt, qkv);
  hipLaunchKernelGGL(attn, dim3(4096), dim3(256), 0, stream, qkv, out);
}

// Round 4
// 193.923 us; speedup vs baseline: 1.1138x; 1.1138x over previous
//
#include <hip/hip_runtime.h>
#include <stdint.h>

#define LOG2E       1.4426950408889634f
#define INV_SQRT32  0.17677669529663687f

using bf16x8 = __attribute__((ext_vector_type(8))) short;
using f32x4  = __attribute__((ext_vector_type(4))) float;

__device__ __forceinline__ unsigned short f2bf(float f) {
  union { float f; uint32_t u; } v; v.f = f;
  uint32_t r = v.u + 0x7fffu + ((v.u >> 16) & 1u);   // RNE
  return (unsigned short)(r >> 16);
}

typedef const __attribute__((address_space(1))) void* gas_ptr;
typedef __attribute__((address_space(3))) void*       las_ptr;
__device__ __forceinline__ void load_lds16(const void* g, void* l) {
  // wave-uniform LDS base; HW scatters lane i -> base + i*16
  __builtin_amdgcn_global_load_lds((gas_ptr)g, (las_ptr)l, 16, 0, 0);
}

// ---------- kernel 1: W (fp32) -> Wcat bf16 [768][256]; bias -> bias_cat fp32 [768]
__global__ __launch_bounds__(256) void convert_w(
    const float* __restrict__ wq, const float* __restrict__ bq,
    const float* __restrict__ wk, const float* __restrict__ bk,
    const float* __restrict__ wv, const float* __restrict__ bv,
    unsigned short* __restrict__ Wcat, float* __restrict__ biasc) {
  int idx = (blockIdx.x * 256 + threadIdx.x) * 4;   // flat into 768*256
  int p = idx >> 16;                                // which projection
  int rem = idx & 0xffff;
  const float* src = (p == 0) ? wq : (p == 1) ? wk : wv;
  float4 v = *(const float4*)(src + rem);
  ushort4 o;
  o.x = f2bf(v.x); o.y = f2bf(v.y); o.z = f2bf(v.z); o.w = f2bf(v.w);
  *(ushort4*)(Wcat + idx) = o;
  if (blockIdx.x < 3) {
    const float* sb = (blockIdx.x == 0) ? bq : (blockIdx.x == 1) ? bk : bv;
    biasc[blockIdx.x * 256 + threadIdx.x] = sb[threadIdx.x];
  }
}

// ---------- kernel 2: x fp32 [b][c][s] -> Xt bf16 [b][s][c]
__global__ __launch_bounds__(256) void transpose_x(const float* __restrict__ x,
                                                   unsigned short* __restrict__ xt) {
  __shared__ float tile[64 * 65];
  int b = blockIdx.z;
  int s0 = blockIdx.x * 64, c0 = blockIdx.y * 64;
  int t = threadIdx.x;
  int sl = t & 63, g = t >> 6;
  const float* xp = x + ((size_t)(b * 256 + c0)) * 4096 + s0 + sl;
#pragma unroll
  for (int ii = 0; ii < 16; ++ii) {
    int cl = g * 16 + ii;
    tile[cl * 65 + sl] = xp[(size_t)cl * 4096];
  }
  __syncthreads();
  // store phase: each thread packs 8 contiguous c into one uint4 store
#pragma unroll
  for (int it = 0; it < 2; ++it) {
    int idx = it * 256 + t;
    int s_loc = idx >> 3, cb = (idx & 7) * 8;
    unsigned short ov[8];
#pragma unroll
    for (int j = 0; j < 8; ++j) ov[j] = f2bf(tile[(cb + j) * 65 + s_loc]);
    *(uint4*)&xt[((size_t)(b * 4096 + s0 + s_loc)) * 256 + c0 + cb] = *(uint4*)ov;
  }
}

// ---------- kernel 3: qkv[b][768][4096] bf16 = Wcat[768][256] * Xt[b][4096][256]^T + bias
// v5: round-2 depth-2 counted-vmcnt pipeline (best measured) + swapped-operand MFMA +
//     LDS-staged epilogue: C tile reuses As/Bs (32KB), stores go out as 256B-contiguous rows.
__global__ __launch_bounds__(256) void gemm_qkv(
    const unsigned short* __restrict__ Wc, const float* __restrict__ biasc,
    const unsigned short* __restrict__ Xt, unsigned short* __restrict__ qkv) {
  __shared__ unsigned short sh[16384];   // As[2][4096] @0 | Bs[2][4096] @8192; reused as C[128][128]
  int blk = blockIdx.x;
  int b = blk / 192;
  int rest = blk - b * 192;
  int mt = rest >> 5, nt = rest & 31;
  int m0 = mt * 128, n0 = nt * 128;
  int tid = threadIdx.x;
  int lane = tid & 63, wave = tid >> 6;
  int quad = lane >> 4, rt = lane & 15;
  int wm = wave >> 1, wn = wave & 1;

  f32x4 acc[4][4];
#pragma unroll
  for (int i = 0; i < 4; ++i)
#pragma unroll
    for (int j = 0; j < 4; ++j) acc[i][j] = (f32x4){0.f, 0.f, 0.f, 0.f};

  // staging: each wave stages rows [wave*32, wave*32+32) of both tiles.
  // LDS dest linear (lane i -> base + 16*i): row = lane>>2, slot = lane&3.
  // swizzle: physical slot p at row r holds logical slot p ^ ((r>>1)&3)
  int lr = lane >> 2;
  int sl_src = (lane & 3) ^ ((lane >> 3) & 3);
  const unsigned short* gA0 = Wc + (size_t)(m0 + wave * 32 + lr) * 256 + sl_src * 8;
  const unsigned short* gA1 = gA0 + 16 * 256;
  const unsigned short* gB0 = Xt + ((size_t)b * 4096 + n0 + wave * 32 + lr) * 256 + sl_src * 8;
  const unsigned short* gB1 = gB0 + 16 * 256;

#define STAGE(bufi, ko)                                                     \
  do {                                                                      \
    load_lds16(gA0 + (ko), &sh[(bufi) * 4096 + wave * 1024]);               \
    load_lds16(gA1 + (ko), &sh[(bufi) * 4096 + wave * 1024 + 512]);         \
    load_lds16(gB0 + (ko), &sh[8192 + (bufi) * 4096 + wave * 1024]);        \
    load_lds16(gB1 + (ko), &sh[8192 + (bufi) * 4096 + wave * 1024 + 512]);  \
  } while (0)

  int rsw = (quad ^ ((rt >> 1) & 3)) * 8;   // swizzled read slot (elements)

  // prologue: 2 chunks in flight, no drain
  STAGE(0, 0);
  STAGE(1, 32);

  // Ledger (4 loads/STAGE, in-order): top of iter k, outstanding = chunk k (4) + k+1 (4)
  //   -> vmcnt(4) retires chunk k; k=7 -> vmcnt(0). End of iter (k+2<8): stage k+2.
#define KSTEP(kc, WAITN)                                                      \
  do {                                                                        \
    asm volatile("s_waitcnt vmcnt(" #WAITN ")" ::: "memory");                 \
    __builtin_amdgcn_s_barrier();                                             \
    __builtin_amdgcn_sched_barrier(0);                                        \
    const unsigned short* A_ = &sh[((kc) & 1) * 4096];                        \
    const unsigned short* B_ = &sh[8192 + ((kc) & 1) * 4096];                 \
    bf16x8 af[4], bfr[4];                                                     \
    _Pragma("unroll")                                                         \
    for (int mi = 0; mi < 4; ++mi)                                            \
      af[mi] = *(const bf16x8*)&A_[(wm * 64 + mi * 16 + rt) * 32 + rsw];      \
    _Pragma("unroll")                                                         \
    for (int ni = 0; ni < 4; ++ni)                                            \
      bfr[ni] = *(const bf16x8*)&B_[(wn * 64 + ni * 16 + rt) * 32 + rsw];     \
    _Pragma("unroll")                                                         \
    for (int mi = 0; mi < 4; ++mi)                                            \
      _Pragma("unroll")                                                       \
      for (int ni = 0; ni < 4; ++ni)                                          \
        acc[mi][ni] = __builtin_amdgcn_mfma_f32_16x16x32_bf16(bfr[ni], af[mi], acc[mi][ni], 0, 0, 0); \
    __builtin_amdgcn_sched_barrier(0);                                        \
    __builtin_amdgcn_s_barrier();                                             \
    if ((kc) + 2 < 8) STAGE((kc) & 1, ((kc) + 2) * 32);                       \
  } while (0)

  KSTEP(0, 4);
  KSTEP(1, 4);
  KSTEP(2, 4);
  KSTEP(3, 4);
  KSTEP(4, 4);
  KSTEP(5, 4);
  KSTEP(6, 4);
  KSTEP(7, 0);
#undef KSTEP
#undef STAGE

  // ---- epilogue: acc -> C_lds (bf16, 16B-granule XOR swizzle) -> 256B-coalesced stores
  // swapped MFMA: lane holds D[s_loc = wn*64+ni*16+quad*4+r][o_loc = wm*64+mi*16+rt]
  // C layout: row = o_loc (256B rows), 16 granules of 16B; physical granule = g ^ (o_loc&7)
  unsigned short* C = sh;   // all K-loop LDS reads complete (final barrier) -> safe reuse
  size_t obase = (size_t)b * 768;
#pragma unroll
  for (int mi = 0; mi < 4; ++mi) {
    int o_loc = wm * 64 + mi * 16 + rt;
    float bo = biasc[m0 + o_loc];
#pragma unroll
    for (int ni = 0; ni < 4; ++ni) {
      int g0 = wn * 8 + ni * 2 + (quad >> 1);      // logical 16B granule
      int pg = g0 ^ (o_loc & 7);                   // swizzled
      ushort4 st;
      st.x = f2bf(acc[mi][ni][0] + bo);
      st.y = f2bf(acc[mi][ni][1] + bo);
      st.z = f2bf(acc[mi][ni][2] + bo);
      st.w = f2bf(acc[mi][ni][3] + bo);
      *(ushort4*)&C[o_loc * 128 + pg * 8 + (quad & 1) * 4] = st;
    }
  }
  __syncthreads();
#pragma unroll
  for (int i = 0; i < 8; ++i) {
    int idx = i * 256 + tid;
    int row = idx >> 4, g = idx & 15;              // 16 lanes -> 256B contiguous per row
    int pg = g ^ (row & 7);
    bf16x8 v = *(const bf16x8*)&C[row * 128 + pg * 8];
    *(bf16x8*)&qkv[(obase + m0 + row) * 4096 + n0 + g * 8] = v;
  }
}

// ---------- kernel 4: per-(b, o) 64x64 attention, MFMA-based (v1, known-good)
// S = Q K^T (contract w), softmax over g, O = P V (contract g)
// LDS layout (36608 B total, phase-overlaid):
//   phase1: Qs[64][72]bf16 @0 (9216), Ks[64][72]bf16 @9216 (9216)
//   phase2: Sf[64][65]f32  @0 (16640), Ps[64][72]bf16 @16640 (9216)
//   Vt[64][72]bf16 @25856 (9216) | red[4][64]f32 @35072 | rowmax @36096 | rowinv @36352
__global__ __launch_bounds__(256) void attn(const unsigned short* __restrict__ qkv,
                                            float* __restrict__ out) {
  __shared__ char shm[36608];
  unsigned short* Qs = (unsigned short*)shm;
  unsigned short* Ks = (unsigned short*)(shm + 9216);
  float*          Sf = (float*)shm;
  unsigned short* Ps = (unsigned short*)(shm + 16640);
  unsigned short* Vt = (unsigned short*)(shm + 25856);
  float* red    = (float*)(shm + 35072);
  float* rowmax = (float*)(shm + 36096);
  float* rowinv = (float*)(shm + 36352);

  int blk = blockIdx.x;
  int b = blk >> 8, o = blk & 255;
  int t = threadIdx.x;
  size_t base = ((size_t)b * 768 + o) * 4096;
  const unsigned short* qg = qkv + base;
  const unsigned short* kg = qkv + base + (size_t)256 * 4096;
  const unsigned short* vg = qkv + base + (size_t)512 * 4096;

  // --- stage Q,K as [h][w] (b128 rows), V transposed as Vt[w][g]
  {
    int h = t >> 2, w0 = (t & 3) * 16;
    const uint4* qp = (const uint4*)(qg + h * 64 + w0);
    const uint4* kp = (const uint4*)(kg + h * 64 + w0);
    uint4 q0 = qp[0], q1 = qp[1];
    uint4 k0 = kp[0], k1 = kp[1];
    *(uint4*)&Qs[h * 72 + w0]     = q0;
    *(uint4*)&Qs[h * 72 + w0 + 8] = q1;
    *(uint4*)&Ks[h * 72 + w0]     = k0;
    *(uint4*)&Ks[h * 72 + w0 + 8] = k1;

    int w = t & 63, gb = (t >> 6) * 16;
    unsigned short vv[16];
#pragma unroll
    for (int j = 0; j < 16; ++j) vv[j] = vg[(size_t)(gb + j) * 64 + w];
    *(uint4*)&Vt[w * 72 + gb]     = ((uint4*)vv)[0];
    *(uint4*)&Vt[w * 72 + gb + 8] = ((uint4*)vv)[1];
  }
  __syncthreads();

  int lane = t & 63, wave = t >> 6;
  int rt = lane & 15, quad = lane >> 4;
  int wm = wave >> 1, wn = wave & 1;

  // --- S = Q K^T via MFMA: 2x2 tiles of 16x16 per wave, K=64 (2 steps)
  f32x4 accs[2][2];
#pragma unroll
  for (int i = 0; i < 2; ++i)
#pragma unroll
    for (int j = 0; j < 2; ++j) accs[i][j] = (f32x4){0.f, 0.f, 0.f, 0.f};
#pragma unroll
  for (int ks = 0; ks < 2; ++ks) {
    int kk = ks * 32 + quad * 8;
    bf16x8 a0 = *(const bf16x8*)&Qs[(wm * 32 + rt) * 72 + kk];
    bf16x8 a1 = *(const bf16x8*)&Qs[(wm * 32 + 16 + rt) * 72 + kk];
    bf16x8 b0 = *(const bf16x8*)&Ks[(wn * 32 + rt) * 72 + kk];
    bf16x8 b1 = *(const bf16x8*)&Ks[(wn * 32 + 16 + rt) * 72 + kk];
    accs[0][0] = __builtin_amdgcn_mfma_f32_16x16x32_bf16(a0, b0, accs[0][0], 0, 0, 0);
    accs[0][1] = __builtin_amdgcn_mfma_f32_16x16x32_bf16(a0, b1, accs[0][1], 0, 0, 0);
    accs[1][0] = __builtin_amdgcn_mfma_f32_16x16x32_bf16(a1, b0, accs[1][0], 0, 0, 0);
    accs[1][1] = __builtin_amdgcn_mfma_f32_16x16x32_bf16(a1, b1, accs[1][1], 0, 0, 0);
  }
  __syncthreads();   // protect Qs/Ks before Sf/Ps overlay writes

  // write S (scaled) to Sf stride 65 (C/D: row=quad*4+reg, col=lane&15)
#pragma unroll
  for (int tm = 0; tm < 2; ++tm)
#pragma unroll
    for (int tn = 0; tn < 2; ++tn)
#pragma unroll
      for (int r = 0; r < 4; ++r)
        Sf[(wm * 32 + tm * 16 + quad * 4 + r) * 65 + wn * 32 + tn * 16 + rt] =
            accs[tm][tn][r] * INV_SQRT32;
  __syncthreads();

  // --- softmax over g: 4 threads/row, 16 elems each (held in regs)
  int hr = t & 63, qt = t >> 6;
  float s[16];
#pragma unroll
  for (int e = 0; e < 16; ++e) s[e] = Sf[hr * 65 + qt * 16 + e];
  float m = s[0];
#pragma unroll
  for (int e = 1; e < 16; ++e) m = fmaxf(m, s[e]);
  red[qt * 64 + hr] = m;
  __syncthreads();
  if (t < 64)
    rowmax[t] = fmaxf(fmaxf(red[t], red[64 + t]), fmaxf(red[128 + t], red[192 + t]));
  __syncthreads();
  float mr = rowmax[hr];
  float ssum = 0.f;
  unsigned short pv[16];
#pragma unroll
  for (int e = 0; e < 16; ++e) {
    float p = exp2f((s[e] - mr) * LOG2E);
    ssum += p;
    pv[e] = f2bf(p);
  }
  *(uint4*)&Ps[hr * 72 + qt * 16]     = ((uint4*)pv)[0];
  *(uint4*)&Ps[hr * 72 + qt * 16 + 8] = ((uint4*)pv)[1];
  red[qt * 64 + hr] = ssum;
  __syncthreads();
  if (t < 64) rowinv[t] = 1.f / (red[t] + red[64 + t] + red[128 + t] + red[192 + t]);
  __syncthreads();

  // --- O = P V via MFMA: A=Ps[h][g], B=Vt[w][g], contract g
  f32x4 acco[2][2];
#pragma unroll
  for (int i = 0; i < 2; ++i)
#pragma unroll
    for (int j = 0; j < 2; ++j) acco[i][j] = (f32x4){0.f, 0.f, 0.f, 0.f};
#pragma unroll
  for (int ks = 0; ks < 2; ++ks) {
    int kk = ks * 32 + quad * 8;
    bf16x8 a0 = *(const bf16x8*)&Ps[(wm * 32 + rt) * 72 + kk];
    bf16x8 a1 = *(const bf16x8*)&Ps[(wm * 32 + 16 + rt) * 72 + kk];
    bf16x8 b0 = *(const bf16x8*)&Vt[(wn * 32 + rt) * 72 + kk];
    bf16x8 b1 = *(const bf16x8*)&Vt[(wn * 32 + 16 + rt) * 72 + kk];
    acco[0][0] = __builtin_amdgcn_mfma_f32_16x16x32_bf16(a0, b0, acco[0][0], 0, 0, 0);
    acco[0][1] = __builtin_amdgcn_mfma_f32_16x16x32_bf16(a0, b1, acco[0][1], 0, 0, 0);
    acco[1][0] = __builtin_amdgcn_mfma_f32_16x16x32_bf16(a1, b0, acco[1][0], 0, 0, 0);
    acco[1][1] = __builtin_amdgcn_mfma_f32_16x16x32_bf16(a1, b1, acco[1][1], 0, 0, 0);
  }

  float* op = out + ((size_t)(b * 256 + o)) * 4096;
#pragma unroll
  for (int tm = 0; tm < 2; ++tm) {
#pragma unroll
    for (int r = 0; r < 4; ++r) {
      int h = wm * 32 + tm * 16 + quad * 4 + r;
      float inv = rowinv[h];
#pragma unroll
      for (int tn = 0; tn < 2; ++tn) {
        int w = wn * 32 + tn * 16 + rt;
        op[h * 64 + w] = acco[tm][tn][r] * inv;
      }
    }
  }
}

extern "C" void kernel_launch(void* const* d_in, const int* in_sizes, int n_in,
                              void* d_out, int out_size, void* d_ws, size_t ws_size,
                              hipStream_t stream) {
  const float* x  = (const float*)d_in[0];
  const float* wq = (const float*)d_in[1];
  const float* bq = (const float*)d_in[2];
  const float* wk = (const float*)d_in[3];
  const float* bk = (const float*)d_in[4];
  const float* wv = (const float*)d_in[5];
  const float* bv = (const float*)d_in[6];
  float* out = (float*)d_out;

  // workspace layout (bytes): Wcat bf16 393216 | bias fp32 3072 | Xt bf16 33554432 | qkv bf16 100663296
  char* ws = (char*)d_ws;
  unsigned short* Wcat  = (unsigned short*)ws;
  float*          biasc = (float*)(ws + 393216);
  unsigned short* Xt    = (unsigned short*)(ws + 396288);
  unsigned short* qkv   = (unsigned short*)(ws + 396288 + 33554432);

  hipLaunchKernelGGL(convert_w, dim3(192), dim3(256), 0, stream,
                     wq, bq, wk, bk, wv, bv, Wcat, biasc);
  hipLaunchKernelGGL(transpose_x, dim3(64, 4, 16), dim3(256), 0, stream, x, Xt);
  hipLaunchKernelGGL(gemm_qkv, dim3(3072), dim3(256), 0, stream, Wcat, biasc, Xt, qkv);
  hipLaunchKernelGGL(attn, dim3(4096), dim3(256), 0, stream, qkv, out);
}